// Round 10
// baseline (335.290 us; speedup 1.0000x reference)
//
#include <hip/hip_runtime.h>
#include <hip/hip_fp16.h>

typedef unsigned int uint;
typedef unsigned short ushort;

typedef __attribute__((ext_vector_type(8))) _Float16 f16x8;
typedef __attribute__((ext_vector_type(4))) float f32x4;

#define TOK 256
#define OUTF 11008
#define INF 4096
#define BN 64
#define NT2 172  // OUTF / BN

__device__ __constant__ float NF4_TBL[16] = {
    -1.0f, -0.6961928009986877f, -0.5250730514526367f, -0.39491748809814453f,
    -0.28444138169288635f, -0.18477343022823334f, -0.09105003625154495f, 0.0f,
    0.07958029955625534f, 0.16093020141124725f, 0.24611230194568634f,
    0.33791524171829224f, 0.44070982933044434f, 0.5626170039176941f,
    0.7229568362236023f, 1.0f};

__device__ __forceinline__ ushort f2h(float f) {
  return __half_as_ushort(__float2half(f));
}

// async global->LDS, 16B per lane; lds base wave-uniform + lane*16
__device__ __forceinline__ void async_cp16(const void* g, void* l) {
  __builtin_amdgcn_global_load_lds(
      (const __attribute__((address_space(1))) uint*)g,
      (__attribute__((address_space(3))) uint*)l, 16, 0, 0);
}

// kernel 1 (prep): pack q int32->nibbles row-major; x fp32->f16; lora_B padded
__global__ void prep_kernel(const int4* __restrict__ qc4, uint* __restrict__ pk,
                            const float4* __restrict__ x4, ushort4* __restrict__ xh4,
                            const float4* __restrict__ lB4, ushort4* __restrict__ lBh4) {
  const int stride = gridDim.x * blockDim.x;
  const int t0 = blockIdx.x * blockDim.x + threadIdx.x;
  for (int d = t0; d < OUTF * INF / 8; d += stride) {
    int4 a = qc4[2 * d];
    int4 b = qc4[2 * d + 1];
    pk[d] = (uint)(a.x & 15) | ((uint)(a.y & 15) << 4) | ((uint)(a.z & 15) << 8) |
            ((uint)(a.w & 15) << 12) | ((uint)(b.x & 15) << 16) | ((uint)(b.y & 15) << 20) |
            ((uint)(b.z & 15) << 24) | ((uint)(b.w & 15) << 28);
  }
  for (int i = t0; i < TOK * INF / 4; i += stride) {
    float4 v = x4[i];
    ushort4 o;
    o.x = f2h(v.x); o.y = f2h(v.y); o.z = f2h(v.z); o.w = f2h(v.w);
    xh4[i] = o;
  }
  for (int i = t0; i < OUTF * 16; i += stride) {
    int n = i >> 4, jq = i & 15;
    ushort4 o = {0, 0, 0, 0};
    if (jq < 4) {
      float4 v = lB4[n * 4 + jq];
      o.x = f2h(v.x); o.y = f2h(v.y); o.z = f2h(v.z); o.w = f2h(v.w);
    }
    lBh4[i] = o;
  }
}

// kernel 2: xa2[m][j] = f16( 2 * sum_k x[m][k]*lora_A[j][k] ), [TOK,64] zero-padded
__global__ __launch_bounds__(1024)
void xa_kernel(const float* __restrict__ x, const float* __restrict__ lA,
               ushort* __restrict__ xa2) {
  const int m = blockIdx.x;
  const int t = threadIdx.x;
  const float4* x4 = (const float4*)(x + (size_t)m * INF);
  const float4* lA4 = (const float4*)lA;
  float4 xv = x4[t];
  float acc[16];
#pragma unroll
  for (int j = 0; j < 16; ++j) {
    float4 a = lA4[j * (INF / 4) + t];
    acc[j] = xv.x * a.x + xv.y * a.y + xv.z * a.z + xv.w * a.w;
  }
#pragma unroll
  for (int j = 0; j < 16; ++j)
#pragma unroll
    for (int s = 32; s > 0; s >>= 1) acc[j] += __shfl_xor(acc[j], s, 64);
  __shared__ float red[16][16];
  const int w = t >> 6, l = t & 63;
  if (l == 0) {
#pragma unroll
    for (int j = 0; j < 16; ++j) red[w][j] = acc[j];
  }
  __syncthreads();
  if (t < 64) {
    ushort v = 0;
    if (t < 16) {
      float s = 0.f;
#pragma unroll
      for (int w2 = 0; w2 < 16; ++w2) s += red[w2][t];
      v = f2h(2.0f * s);
    }
    xa2[m * 64 + t] = v;
  }
}

// kernel 3: fused dequant GEMM. A-frags DIRECT from L2-hot xh (no Abuf);
// packed q via DMA->Qbuf (double-buffered); table dequant -> Bbuf (double-
// buffered, swizzled); ONE barrier per 64-k step.
__global__ __launch_bounds__(256, 3)
void gemm_kernel(const uint* __restrict__ pk, const float* __restrict__ am,
                 const ushort* __restrict__ xh, const ushort* __restrict__ lBh,
                 const ushort* __restrict__ xa2, float* __restrict__ dest, int nst) {
  __shared__ ushort Bbuf[2][64 * 64];  // 16 KB, octet-swizzled
  __shared__ uint Qbuf[2][512];        // 4 KB packed codes (2 KB/step)
  __shared__ float Qax[2][1024];       // 8 KB amax groups (16 k-blocks each)
  __shared__ __half2 tbl[256];         // byte -> (nf4[lo], nf4[hi]) unscaled

  const int tid = threadIdx.x;
  const int w = tid >> 6;
  const int l = tid & 63;
  const int chunk = l >> 4;  // 0..3
  const int rlo = l & 15;
  const int split = blockIdx.x / NT2;
  const int ntile = blockIdx.x - split * NT2;
  const int n0 = ntile * BN;
  const int kb0 = split * nst;  // in 64-k blocks

  tbl[tid & 255] = __halves2half2(__float2half(NF4_TBL[tid & 15]),
                                  __float2half(NF4_TBL[(tid >> 4) & 15]));

  // A direct-load base pointers (a-frag: m=lane&15, k=(lane>>4)*8+j — verified)
  const ushort* aptr[4];
#pragma unroll
  for (int mt = 0; mt < 4; ++mt)
    aptr[mt] = xh + (size_t)(w * 64 + mt * 16 + rlo) * INF + chunk * 8 + kb0 * 64;

  // cooperative dequant mapping (proven R8): thread (dr,w) -> row dr, octets w / w+4
  const int dr = tid & 63;
  const int p7 = dr & 7;
  const int bw0 = dr * 64 + ((w ^ p7) << 3);
  const int bw1 = dr * 64 + (((w + 4) ^ p7) << 3);

  // b-frag read offsets (swizzle-matched, proven R8)
  int boff[2][4];
#pragma unroll
  for (int ks2 = 0; ks2 < 2; ++ks2)
#pragma unroll
    for (int nt = 0; nt < 4; ++nt)
      boff[ks2][nt] = (nt * 16 + rlo) * 64 + (((ks2 * 4 + chunk) ^ (rlo & 7)) << 3);

  f32x4 acc[4][4];
#pragma unroll
  for (int mt = 0; mt < 4; ++mt)
#pragma unroll
    for (int nt = 0; nt < 4; ++nt) acc[mt][nt] = (f32x4){0.f, 0.f, 0.f, 0.f};

  // prologue: Qax group 0, codes for step 0; then dequant step 0, DMA step 1
  if (w == 0) {
#pragma unroll
    for (int j = 0; j < 4; ++j)
      async_cp16(am + (size_t)(n0 + l) * 64 + kb0 + j * 4, (char*)&Qax[0][0] + j * 1024);
#pragma unroll
    for (int j = 0; j < 2; ++j)
      async_cp16((const char*)pk + (size_t)(n0 + l) * 2048 + (size_t)kb0 * 32 + j * 16,
                 (char*)&Qbuf[0][0] + j * 1024);
  }
  __syncthreads();
  {  // dequant step 0 -> Bbuf[0]
    uint q0 = Qbuf[0][dr * 4 + w];
    uint q1 = Qbuf[0][256 + dr * 4 + w];
    __half2 ax2 = __float2half2_rn(Qax[0][dr * 4]);
    union { __half2 h[4]; f16x8 v; } u;
    u.h[0] = __hmul2(tbl[q0 & 255], ax2);
    u.h[1] = __hmul2(tbl[(q0 >> 8) & 255], ax2);
    u.h[2] = __hmul2(tbl[(q0 >> 16) & 255], ax2);
    u.h[3] = __hmul2(tbl[q0 >> 24], ax2);
    *(f16x8*)&Bbuf[0][bw0] = u.v;
    u.h[0] = __hmul2(tbl[q1 & 255], ax2);
    u.h[1] = __hmul2(tbl[(q1 >> 8) & 255], ax2);
    u.h[2] = __hmul2(tbl[(q1 >> 16) & 255], ax2);
    u.h[3] = __hmul2(tbl[q1 >> 24], ax2);
    *(f16x8*)&Bbuf[0][bw1] = u.v;
  }
  if (w == 0 && nst > 1) {
#pragma unroll
    for (int j = 0; j < 2; ++j)
      async_cp16((const char*)pk + (size_t)(n0 + l) * 2048 + (size_t)(kb0 + 1) * 32 + j * 16,
                 (char*)&Qbuf[1][0] + j * 1024);
  }

  for (int s = 0; s < nst; ++s) {
    const int p = s & 1;
    __syncthreads();  // Bbuf[p] visible; Qbuf[p^1] DMA drained

    // dequant step s+1 from Qbuf[p^1] -> Bbuf[p^1]
    if (s + 1 < nst) {
      const int t1 = s + 1;
      uint q0 = Qbuf[p ^ 1][dr * 4 + w];
      uint q1 = Qbuf[p ^ 1][256 + dr * 4 + w];
      __half2 ax2 = __float2half2_rn(Qax[(t1 >> 4) & 1][((t1 & 15) >> 2) * 256 + dr * 4 + (t1 & 3)]);
      union { __half2 h[4]; f16x8 v; } u;
      u.h[0] = __hmul2(tbl[q0 & 255], ax2);
      u.h[1] = __hmul2(tbl[(q0 >> 8) & 255], ax2);
      u.h[2] = __hmul2(tbl[(q0 >> 16) & 255], ax2);
      u.h[3] = __hmul2(tbl[q0 >> 24], ax2);
      *(f16x8*)&Bbuf[p ^ 1][bw0] = u.v;
      u.h[0] = __hmul2(tbl[q1 & 255], ax2);
      u.h[1] = __hmul2(tbl[(q1 >> 8) & 255], ax2);
      u.h[2] = __hmul2(tbl[(q1 >> 16) & 255], ax2);
      u.h[3] = __hmul2(tbl[q1 >> 24], ax2);
      *(f16x8*)&Bbuf[p ^ 1][bw1] = u.v;
    }
    // DMA codes for step s+2 into Qbuf[p]; amax group reload for ks<4 fallback
    if (w == 0 && s + 2 < nst) {
#pragma unroll
      for (int j = 0; j < 2; ++j)
        async_cp16((const char*)pk + (size_t)(n0 + l) * 2048 + (size_t)(kb0 + s + 2) * 32 + j * 16,
                   (char*)&Qbuf[p][0] + j * 1024);
      if (((s + 2) & 15) == 0) {
#pragma unroll
        for (int j = 0; j < 4; ++j)
          async_cp16(am + (size_t)(n0 + l) * 64 + kb0 + s + 2 + j * 4,
                     (char*)&Qax[((s + 2) >> 4) & 1][0] + j * 1024);
      }
    }

    // A-frags direct from L2 + 32 MFMAs
#pragma unroll
    for (int ks2 = 0; ks2 < 2; ++ks2) {
      f16x8 a[4], b[4];
#pragma unroll
      for (int mt = 0; mt < 4; ++mt) a[mt] = *(const f16x8*)(aptr[mt] + s * 64 + ks2 * 32);
#pragma unroll
      for (int nt = 0; nt < 4; ++nt) b[nt] = *(const f16x8*)&Bbuf[p][boff[ks2][nt]];
#pragma unroll
      for (int mt = 0; mt < 4; ++mt)
#pragma unroll
        for (int nt = 0; nt < 4; ++nt)
          acc[mt][nt] = __builtin_amdgcn_mfma_f32_16x16x32_f16(a[mt], b[nt], acc[mt][nt], 0, 0, 0);
    }
  }

  if (split == 0) {
    // lora K-extension: k in [0,32) (rank 16 + zero pad); direct register frags
    f16x8 a_l[4], b_l[4];
#pragma unroll
    for (int mt = 0; mt < 4; ++mt)
      a_l[mt] = *(const f16x8*)(xa2 + (size_t)(w * 64 + mt * 16 + rlo) * 64 + chunk * 8);
#pragma unroll
    for (int nt = 0; nt < 4; ++nt)
      b_l[nt] = *(const f16x8*)(lBh + (size_t)(n0 + nt * 16 + rlo) * 64 + chunk * 8);
#pragma unroll
    for (int mt = 0; mt < 4; ++mt)
#pragma unroll
      for (int nt = 0; nt < 4; ++nt)
        acc[mt][nt] = __builtin_amdgcn_mfma_f32_16x16x32_f16(a_l[mt], b_l[nt], acc[mt][nt], 0, 0, 0);
  }

  // epilogue: C/D layout col=lane&15, row=(lane>>4)*4+reg; each split owns a slice
  float* dst = dest + (size_t)split * TOK * OUTF;
#pragma unroll
  for (int mt = 0; mt < 4; ++mt) {
#pragma unroll
    for (int nt = 0; nt < 4; ++nt) {
      int c = n0 + nt * 16 + rlo;
#pragma unroll
      for (int r = 0; r < 4; ++r) {
        int row = w * 64 + mt * 16 + chunk * 4 + r;
        dst[(size_t)row * OUTF + c] = acc[mt][nt][r];
      }
    }
  }
}

// kernel 4: sum K-split partials -> out
__global__ void reduce_kernel(const float4* __restrict__ part, float4* __restrict__ out,
                              int ks) {
  const int QN = TOK * OUTF / 4;
  int i = blockIdx.x * blockDim.x + threadIdx.x;
  if (i < QN) {
    float4 s = part[i];
    for (int s2 = 1; s2 < ks; ++s2) {
      float4 p = part[(size_t)s2 * QN + i];
      s.x += p.x; s.y += p.y; s.z += p.z; s.w += p.w;
    }
    out[i] = s;
  }
}

extern "C" void kernel_launch(void* const* d_in, const int* in_sizes, int n_in,
                              void* d_out, int out_size, void* d_ws, size_t ws_size,
                              hipStream_t stream) {
  const float* x = (const float*)d_in[0];
  const int* qc = (const int*)d_in[1];
  const float* am = (const float*)d_in[2];
  const float* lA = (const float*)d_in[3];
  const float* lB = (const float*)d_in[4];
  float* out = (float*)d_out;

  const size_t off_lB = (size_t)TOK * INF * 2;             // 2.10 MB
  const size_t off_xa2 = off_lB + (size_t)OUTF * 64 * 2;   // +1.41 MB
  const size_t off_pk = off_xa2 + (size_t)TOK * 64 * 2;    // +32 KB  = 3,538,944
  const size_t off_part = off_pk + (size_t)OUTF * INF / 2; // +22.5 MB = 26,083,328
  const size_t part_bytes = (size_t)TOK * OUTF * 4;        // 11.27 MB per split

  ushort* xh = (ushort*)d_ws;
  ushort* lBh = (ushort*)((char*)d_ws + off_lB);
  ushort* xa2 = (ushort*)((char*)d_ws + off_xa2);
  uint* pk = (uint*)((char*)d_ws + off_pk);
  float* part = (float*)((char*)d_ws + off_part);

  int ks = 1;
  if (ws_size >= off_part + 4 * part_bytes) ks = 4;  // ws ~688 MB observed -> ks=4
  else if (ws_size >= off_part + 2 * part_bytes) ks = 2;
  float* dest = (ks == 1) ? out : part;

  prep_kernel<<<4096, 256, 0, stream>>>((const int4*)qc, pk, (const float4*)x,
                                        (ushort4*)xh, (const float4*)lB, (ushort4*)lBh);
  xa_kernel<<<TOK, 1024, 0, stream>>>(x, lA, xa2);
  gemm_kernel<<<NT2 * ks, 256, 0, stream>>>(pk, am, xh, lBh, xa2, dest, 64 / ks);
  if (ks > 1)
    reduce_kernel<<<(TOK * OUTF / 4 + 255) / 256, 256, 0, stream>>>((const float4*)part,
                                                                    (float4*)out, ks);
}

// Round 11
// 314.183 us; speedup vs baseline: 1.0672x; 1.0672x over previous
//
#include <hip/hip_runtime.h>
#include <hip/hip_fp16.h>

typedef unsigned int uint;
typedef unsigned short ushort;

typedef __attribute__((ext_vector_type(8))) _Float16 f16x8;
typedef __attribute__((ext_vector_type(4))) float f32x4;

#define TOK 256
#define OUTF 11008
#define INF 4096
#define BM 256
#define BN 64
#define NT2 172  // OUTF / BN
#define PREP_BLKS 4096

__device__ __constant__ float NF4_TBL[16] = {
    -1.0f, -0.6961928009986877f, -0.5250730514526367f, -0.39491748809814453f,
    -0.28444138169288635f, -0.18477343022823334f, -0.09105003625154495f, 0.0f,
    0.07958029955625534f, 0.16093020141124725f, 0.24611230194568634f,
    0.33791524171829224f, 0.44070982933044434f, 0.5626170039176941f,
    0.7229568362236023f, 1.0f};

__device__ __forceinline__ ushort f2h(float f) {
  return __half_as_ushort(__float2half(f));
}

// async global->LDS, 16B per lane; lds base wave-uniform + lane*16
__device__ __forceinline__ void async_cp16(const void* g, void* l) {
  __builtin_amdgcn_global_load_lds(
      (const __attribute__((address_space(1))) uint*)g,
      (__attribute__((address_space(3))) uint*)l, 16, 0, 0);
}

// kernel 1 (fused): blocks [0,PREP_BLKS) pack q->nibbles + convert x/lB;
// blocks [PREP_BLKS, PREP_BLKS+TOK) compute xa2 (overlaps the BW-bound pack).
__global__ __launch_bounds__(256)
void prep_kernel(const int4* __restrict__ qc4, uint* __restrict__ pk,
                 const float4* __restrict__ x4, ushort4* __restrict__ xh4,
                 const float4* __restrict__ lB4, ushort4* __restrict__ lBh4,
                 const float* __restrict__ x, const float* __restrict__ lA,
                 ushort* __restrict__ xa2) {
  if (blockIdx.x < PREP_BLKS) {
    const int stride = PREP_BLKS * blockDim.x;
    const int t0 = blockIdx.x * blockDim.x + threadIdx.x;
    for (int d = t0; d < OUTF * INF / 8; d += stride) {
      int4 a = qc4[2 * d];
      int4 b = qc4[2 * d + 1];
      pk[d] = (uint)(a.x & 15) | ((uint)(a.y & 15) << 4) | ((uint)(a.z & 15) << 8) |
              ((uint)(a.w & 15) << 12) | ((uint)(b.x & 15) << 16) |
              ((uint)(b.y & 15) << 20) | ((uint)(b.z & 15) << 24) |
              ((uint)(b.w & 15) << 28);
    }
    for (int i = t0; i < TOK * INF / 4; i += stride) {
      float4 v = x4[i];
      ushort4 o;
      o.x = f2h(v.x); o.y = f2h(v.y); o.z = f2h(v.z); o.w = f2h(v.w);
      xh4[i] = o;
    }
    for (int i = t0; i < OUTF * 16; i += stride) {
      int n = i >> 4, jq = i & 15;
      ushort4 o = {0, 0, 0, 0};
      if (jq < 4) {
        float4 v = lB4[n * 4 + jq];
        o.x = f2h(v.x); o.y = f2h(v.y); o.z = f2h(v.z); o.w = f2h(v.w);
      }
      lBh4[i] = o;
    }
  } else {
    // xa: one block per token m; xa2[m][j] = f16(2 * sum_k x[m][k]*lA[j][k])
    const int m = blockIdx.x - PREP_BLKS;
    const int t = threadIdx.x;
    const float4* xm4 = (const float4*)(x + (size_t)m * INF);
    const float4* lA4 = (const float4*)lA;
    float4 xv[4];
#pragma unroll
    for (int c = 0; c < 4; ++c) xv[c] = xm4[c * 256 + t];
    float acc[16];
#pragma unroll
    for (int j = 0; j < 16; ++j) {
      acc[j] = 0.f;
#pragma unroll
      for (int c = 0; c < 4; ++c) {
        float4 a = lA4[j * (INF / 4) + c * 256 + t];
        acc[j] += xv[c].x * a.x + xv[c].y * a.y + xv[c].z * a.z + xv[c].w * a.w;
      }
    }
#pragma unroll
    for (int j = 0; j < 16; ++j)
#pragma unroll
      for (int s = 32; s > 0; s >>= 1) acc[j] += __shfl_xor(acc[j], s, 64);
    __shared__ float red[4][16];
    const int w = t >> 6, l = t & 63;
    if (l == 0) {
#pragma unroll
      for (int j = 0; j < 16; ++j) red[w][j] = acc[j];
    }
    __syncthreads();
    if (t < 64) {
      ushort v = 0;
      if (t < 16) {
        float s = red[0][t] + red[1][t] + red[2][t] + red[3][t];
        v = f2h(2.0f * s);
      }
      xa2[m * 64 + t] = v;
    }
  }
}

// kernel 2: K-split fused dequant GEMM (R8 skeleton, proven). Delta vs R8:
// Qbuf double-buffered and q(s+1) issued immediately after barrier A(s),
// giving it dequant+barrierB+MFMA of slack before its drain at barrier A(s+1).
__global__ __launch_bounds__(256, 3)
void gemm_kernel(const uint* __restrict__ pk, const float* __restrict__ am,
                 const ushort* __restrict__ xh, const ushort* __restrict__ lBh,
                 const ushort* __restrict__ xa2, float* __restrict__ dest, int nst) {
  __shared__ ushort Abuf[BM * 64];  // 32 KB, octet-swizzled (proven R3..R8)
  __shared__ ushort Bbuf[64 * 64];  // 8 KB, octet-swizzled
  __shared__ uint Qbuf[2][512];     // 4 KB: packed codes, double-buffered
  __shared__ float Qax[1024];       // 4 KB: one group of 16 k-blocks of amax
  __shared__ __half2 tbl[256];      // byte -> (nf4[lo], nf4[hi]) unscaled

  const int tid = threadIdx.x;
  const int w = tid >> 6;
  const int l = tid & 63;
  const int chunk = l >> 4;  // 0..3
  const int rlo = l & 15;
  const int split = blockIdx.x / NT2;
  const int ntile = blockIdx.x - split * NT2;
  const int n0 = ntile * BN;
  const int kb0 = split * nst;  // in 64-k blocks

  tbl[tid & 255] = __halves2half2(__float2half(NF4_TBL[tid & 15]),
                                  __float2half(NF4_TBL[(tid >> 4) & 15]));

  // A staging geometry (verified R3/R5/R7/R8)
  const int arow = w * 8 + (l >> 3);
  const int acol = ((l & 7) ^ (l >> 3)) << 3;
  int aoff[2][4];
#pragma unroll
  for (int ks2 = 0; ks2 < 2; ++ks2) {
    const int cc = ks2 * 4 + chunk;
#pragma unroll
    for (int mt = 0; mt < 4; ++mt)
      aoff[ks2][mt] = (w * 64 + mt * 16 + rlo) * 64 + ((cc ^ (l & 7)) << 3);
  }

  // cooperative dequant mapping (proven R8): thread (dr,w) -> row dr, octets w / w+4
  const int dr = tid & 63;
  const int p7 = dr & 7;
  const int bw0 = dr * 64 + ((w ^ p7) << 3);
  const int bw1 = dr * 64 + (((w + 4) ^ p7) << 3);

  // b-frag LDS read offsets (swizzle-matched, proven R8)
  int boff[2][4];
#pragma unroll
  for (int ks2 = 0; ks2 < 2; ++ks2)
#pragma unroll
    for (int nt = 0; nt < 4; ++nt)
      boff[ks2][nt] = (nt * 16 + rlo) * 64 + (((ks2 * 4 + chunk) ^ (rlo & 7)) << 3);

  f32x4 acc[4][4];
#pragma unroll
  for (int mt = 0; mt < 4; ++mt)
#pragma unroll
    for (int nt = 0; nt < 4; ++nt) acc[mt][nt] = (f32x4){0.f, 0.f, 0.f, 0.f};

  // prologue: A(0), q(0) -> Qbuf[0], Qax group 0
  if (w == 0) {
#pragma unroll
    for (int j = 0; j < 4; ++j)
      async_cp16(am + (size_t)(n0 + l) * 64 + kb0 + j * 4, (char*)Qax + j * 1024);
#pragma unroll
    for (int j = 0; j < 2; ++j)
      async_cp16((const char*)pk + (size_t)(n0 + l) * 2048 + (size_t)kb0 * 32 + j * 16,
                 (char*)&Qbuf[0][0] + j * 1024);
  }
#pragma unroll
  for (int i = 0; i < 8; ++i) {
    const ushort* g = xh + (size_t)(i * 32 + arow) * INF + kb0 * 64 + acol;
    async_cp16(g, &Abuf[(i * 256 + w * 64) * 8]);
  }

  for (int s = 0; s < nst; ++s) {
    const int p = s & 1;
    __syncthreads();  // barrier A: drains A(s), q(s) (and Qax when reloaded)

    // issue q(s+1) NOW — Qbuf[p^1] was consumed at dequant(s-1), safe to overwrite
    if (w == 0 && s + 1 < nst) {
#pragma unroll
      for (int j = 0; j < 2; ++j)
        async_cp16((const char*)pk + (size_t)(n0 + l) * 2048 + (size_t)(kb0 + s + 1) * 32 + j * 16,
                   (char*)&Qbuf[p ^ 1][0] + j * 1024);
    }

    // dequant q(s) from Qbuf[p] -> Bbuf
    {
      const int sl = s & 15;
      uint q0 = Qbuf[p][dr * 4 + w];
      uint q1 = Qbuf[p][256 + dr * 4 + w];
      __half2 ax2 = __float2half2_rn(Qax[(sl >> 2) * 256 + dr * 4 + (sl & 3)]);
      union { __half2 h[4]; f16x8 v; } u;
      u.h[0] = __hmul2(tbl[q0 & 255], ax2);
      u.h[1] = __hmul2(tbl[(q0 >> 8) & 255], ax2);
      u.h[2] = __hmul2(tbl[(q0 >> 16) & 255], ax2);
      u.h[3] = __hmul2(tbl[q0 >> 24], ax2);
      *(f16x8*)&Bbuf[bw0] = u.v;
      u.h[0] = __hmul2(tbl[q1 & 255], ax2);
      u.h[1] = __hmul2(tbl[(q1 >> 8) & 255], ax2);
      u.h[2] = __hmul2(tbl[(q1 >> 16) & 255], ax2);
      u.h[3] = __hmul2(tbl[q1 >> 24], ax2);
      *(f16x8*)&Bbuf[bw1] = u.v;
    }
    // A frags to registers
    f16x8 areg[2][4];
#pragma unroll
    for (int ks2 = 0; ks2 < 2; ++ks2)
#pragma unroll
      for (int mt = 0; mt < 4; ++mt) areg[ks2][mt] = *(const f16x8*)&Abuf[aoff[ks2][mt]];

    __syncthreads();  // barrier B: Bbuf ready; Abuf/Qbuf[p] consumed

    // issue A(s+1) into Abuf (reg pulls done); Qax reload only on ks<4 fallback
    if (s + 1 < nst) {
      const int kb = kb0 + s + 1;
#pragma unroll
      for (int i = 0; i < 8; ++i) {
        const ushort* g = xh + (size_t)(i * 32 + arow) * INF + kb * 64 + acol;
        async_cp16(g, &Abuf[(i * 256 + w * 64) * 8]);
      }
      if (w == 0 && ((s + 1) & 15) == 0) {
#pragma unroll
        for (int j = 0; j < 4; ++j)
          async_cp16(am + (size_t)(n0 + l) * 64 + kb + j * 4, (char*)Qax + j * 1024);
      }
    }

    // compute: 32 MFMAs from registers + Bbuf
#pragma unroll
    for (int ks2 = 0; ks2 < 2; ++ks2) {
      f16x8 b[4];
#pragma unroll
      for (int nt = 0; nt < 4; ++nt) b[nt] = *(const f16x8*)&Bbuf[boff[ks2][nt]];
#pragma unroll
      for (int mt = 0; mt < 4; ++mt)
#pragma unroll
        for (int nt = 0; nt < 4; ++nt)
          acc[mt][nt] = __builtin_amdgcn_mfma_f32_16x16x32_f16(areg[ks2][mt], b[nt], acc[mt][nt], 0, 0, 0);
    }
  }

  if (split == 0) {
    // lora K-extension: k in [0,32) (rank 16 + zero pad); direct register frags
    f16x8 a_l[4], b_l[4];
#pragma unroll
    for (int mt = 0; mt < 4; ++mt)
      a_l[mt] = *(const f16x8*)(xa2 + (size_t)(w * 64 + mt * 16 + rlo) * 64 + chunk * 8);
#pragma unroll
    for (int nt = 0; nt < 4; ++nt)
      b_l[nt] = *(const f16x8*)(lBh + (size_t)(n0 + nt * 16 + rlo) * 64 + chunk * 8);
#pragma unroll
    for (int mt = 0; mt < 4; ++mt)
#pragma unroll
      for (int nt = 0; nt < 4; ++nt)
        acc[mt][nt] = __builtin_amdgcn_mfma_f32_16x16x32_f16(a_l[mt], b_l[nt], acc[mt][nt], 0, 0, 0);
  }

  // epilogue: C/D layout col=lane&15, row=(lane>>4)*4+reg; each split owns a slice
  float* dst = dest + (size_t)split * TOK * OUTF;
#pragma unroll
  for (int mt = 0; mt < 4; ++mt) {
#pragma unroll
    for (int nt = 0; nt < 4; ++nt) {
      int c = n0 + nt * 16 + rlo;
#pragma unroll
      for (int r = 0; r < 4; ++r) {
        int row = w * 64 + mt * 16 + chunk * 4 + r;
        dst[(size_t)row * OUTF + c] = acc[mt][nt][r];
      }
    }
  }
}

// kernel 3: sum K-split partials -> out
__global__ void reduce_kernel(const float4* __restrict__ part, float4* __restrict__ out,
                              int ks) {
  const int QN = TOK * OUTF / 4;
  int i = blockIdx.x * blockDim.x + threadIdx.x;
  if (i < QN) {
    float4 s = part[i];
    for (int s2 = 1; s2 < ks; ++s2) {
      float4 p = part[(size_t)s2 * QN + i];
      s.x += p.x; s.y += p.y; s.z += p.z; s.w += p.w;
    }
    out[i] = s;
  }
}

extern "C" void kernel_launch(void* const* d_in, const int* in_sizes, int n_in,
                              void* d_out, int out_size, void* d_ws, size_t ws_size,
                              hipStream_t stream) {
  const float* x = (const float*)d_in[0];
  const int* qc = (const int*)d_in[1];
  const float* am = (const float*)d_in[2];
  const float* lA = (const float*)d_in[3];
  const float* lB = (const float*)d_in[4];
  float* out = (float*)d_out;

  const size_t off_lB = (size_t)TOK * INF * 2;             // 2.10 MB
  const size_t off_xa2 = off_lB + (size_t)OUTF * 64 * 2;   // +1.41 MB
  const size_t off_pk = off_xa2 + (size_t)TOK * 64 * 2;    // +32 KB  = 3,538,944
  const size_t off_part = off_pk + (size_t)OUTF * INF / 2; // +22.5 MB = 26,083,328
  const size_t part_bytes = (size_t)TOK * OUTF * 4;        // 11.27 MB per split

  ushort* xh = (ushort*)d_ws;
  ushort* lBh = (ushort*)((char*)d_ws + off_lB);
  ushort* xa2 = (ushort*)((char*)d_ws + off_xa2);
  uint* pk = (uint*)((char*)d_ws + off_pk);
  float* part = (float*)((char*)d_ws + off_part);

  int ks = 1;
  if (ws_size >= off_part + 4 * part_bytes) ks = 4;  // ws ~688 MB observed -> ks=4
  else if (ws_size >= off_part + 2 * part_bytes) ks = 2;
  float* dest = (ks == 1) ? out : part;

  prep_kernel<<<PREP_BLKS + TOK, 256, 0, stream>>>(
      (const int4*)qc, pk, (const float4*)x, (ushort4*)xh,
      (const float4*)lB, (ushort4*)lBh, x, lA, xa2);
  gemm_kernel<<<NT2 * ks, 256, 0, stream>>>(pk, am, xh, lBh, xa2, dest, 64 / ks);
  if (ks > 1)
    reduce_kernel<<<(TOK * OUTF / 4 + 255) / 256, 256, 0, stream>>>((const float4*)part,
                                                                    (float4*)out, ks);
}